// Round 1
// baseline (308.486 us; speedup 1.0000x reference)
//
#include <hip/hip_runtime.h>
#include <hip/hip_bf16.h>

#define N_ROWS 262144
#define D_IN 162
#define H_DIM 256
#define K_DIM 30

using bf16_t = __hip_bfloat16;
typedef __attribute__((ext_vector_type(8))) short bf16x8;
typedef __attribute__((ext_vector_type(4))) float f32x4;

// bf16-element index into a 64x256 swizzled LDS tile.
// Row stride 512B would put all 16 frag-rows in the same 4 banks; the XOR
// spreads 8 consecutive rows across 8 distinct 16B slots (2-way = free).
__device__ __forceinline__ int swz_idx(int row, int col) {
  int byte = (row << 9) + (col << 1);
  byte ^= (row & 7) << 4;
  return byte >> 1;
}

__device__ __forceinline__ float softplus_f(float x) {
  return (x > 15.f) ? x : log1pf(__expf(x));
}

// ---------------- weight packing: fp32 [K][N] -> bf16 [kb][Np][32] ------------
// Element (k,n) lives at ((k/32)*Np + n)*32 + (k%32): each MFMA B-fragment read
// is then one contiguous 16B load per lane.
__global__ void pack_b_kernel(const float* __restrict__ src, bf16_t* __restrict__ dst,
                              int K, int N, int Np, int KB) {
  int idx = blockIdx.x * 256 + threadIdx.x;
  int total = KB * Np * 32;
  if (idx >= total) return;
  int ks = idx & 31;
  int n  = (idx >> 5) % Np;
  int kb = idx / (32 * Np);
  int k  = kb * 32 + ks;
  float v = (k < K && n < N) ? src[k * N + n] : 0.f;
  dst[idx] = __float2bfloat16(v);
}

// Wa and Wb packed side by side: cols 0..29 = Wa, cols 32..61 = Wb, rest zero.
// This makes the lane holding alpha_j (frag n) also hold beta_j (frag n+2).
__global__ void pack_ab_kernel(const float* __restrict__ Wa, const float* __restrict__ Wb,
                               bf16_t* __restrict__ dst) {
  int idx = blockIdx.x * 256 + threadIdx.x;   // total 8*64*32 = 16384
  if (idx >= 8 * 64 * 32) return;
  int ks = idx & 31;
  int n  = (idx >> 5) & 63;
  int kb = idx >> 11;
  int k  = kb * 32 + ks;
  float v = 0.f;
  if (n < 30)                 v = Wa[k * 30 + n];
  else if (n >= 32 && n < 62) v = Wb[k * 30 + (n - 32)];
  dst[idx] = __float2bfloat16(v);
}

// ---------------- fused forward ------------------------------------------------
// A-fragment fill: lane l -> row = l&15, k = 32*kb + 8*(l>>4) + j (j=0..7).
// B-fragment fill uses the same (l>>4, j)->k map, so the contraction is correct
// for any internal hardware k-order (both operands permuted identically).
template<int KB, int NP>
__device__ __forceinline__ void gemm_tile(const bf16_t* __restrict__ A,
                                          const bf16_t* __restrict__ Bp,
                                          int colBase, int lr, int lg,
                                          f32x4 acc[4][4]) {
#pragma unroll
  for (int kb = 0; kb < KB; ++kb) {
    bf16x8 a[4], b[4];
#pragma unroll
    for (int m = 0; m < 4; ++m)
      a[m] = *reinterpret_cast<const bf16x8*>(A + swz_idx(16 * m + lr, kb * 32 + 8 * lg));
#pragma unroll
    for (int n = 0; n < 4; ++n)
      b[n] = *reinterpret_cast<const bf16x8*>(Bp + ((kb * NP + colBase + 16 * n + lr) << 5) + 8 * lg);
#pragma unroll
    for (int m = 0; m < 4; ++m)
#pragma unroll
      for (int n = 0; n < 4; ++n)
        acc[m][n] = __builtin_amdgcn_mfma_f32_16x16x32_bf16(a[m], b[n], acc[m][n], 0, 0, 0);
  }
}

// relu(acc + bias) -> bf16 into swizzled 64x256 LDS tile (wave's 64-col slice)
__device__ __forceinline__ void epilogue_relu(f32x4 acc[4][4], const float* __restrict__ bias,
                                              bf16_t* __restrict__ Out, int colBase,
                                              int lr, int lg) {
#pragma unroll
  for (int n = 0; n < 4; ++n) {
    int col = colBase + 16 * n + lr;
    float bv = bias[col];
#pragma unroll
    for (int m = 0; m < 4; ++m)
#pragma unroll
      for (int i = 0; i < 4; ++i) {
        float x = acc[m][n][i] + bv;
        x = fmaxf(x, 0.f);
        Out[swz_idx(16 * m + 4 * lg + i, col)] = __float2bfloat16(x);
      }
  }
}

__launch_bounds__(256, 2)
__global__ void usdn_fused(const float* __restrict__ Yh, const float* __restrict__ u,
                           const float* __restrict__ b1, const float* __restrict__ b2,
                           const float* __restrict__ ba, const float* __restrict__ bb,
                           const float* __restrict__ bd1, const float* __restrict__ bd2,
                           const bf16_t* __restrict__ Wp1, const bf16_t* __restrict__ Wp2,
                           const bf16_t* __restrict__ Wpab, const bf16_t* __restrict__ Wpd1,
                           const bf16_t* __restrict__ Wpd2,
                           float* __restrict__ outRecon, float* __restrict__ outAlpha,
                           float* __restrict__ outBeta, float* __restrict__ outPi) {
  __shared__ bf16_t bufA[64 * 256];   // 32 KB
  __shared__ bf16_t bufB[64 * 256];   // 32 KB  (also aliased as vbuf fp32[64][33])

  const int tid = threadIdx.x;
  const int w  = tid >> 6;
  const int l  = tid & 63;
  const int lr = l & 15;
  const int lg = l >> 4;
  const int r0 = blockIdx.x << 6;

  // ---- stage Yh tile (64 x 162 fp32, contiguous) -> bufA bf16, zero pad to k<192
  {
    const float4* src = reinterpret_cast<const float4*>(Yh + (size_t)r0 * D_IN);
    for (int i = tid; i < (64 * D_IN) / 4; i += 256) {
      float4 f = src[i];
      int base = i << 2;
#pragma unroll
      for (int e = 0; e < 4; ++e) {
        int idx = base + e;
        int row = idx / D_IN;
        int col = idx - row * D_IN;
        bufA[swz_idx(row, col)] = __float2bfloat16((&f.x)[e]);
      }
    }
    for (int i = tid; i < 64 * (192 - D_IN); i += 256) {
      int row = i / 30;
      int col = D_IN + (i - row * 30);
      bufA[swz_idx(row, col)] = __float2bfloat16(0.f);
    }
  }
  __syncthreads();

  // ---- GEMM1: h1 = relu(Yh @ W1 + b1), K=192(pad) -> bufB
  {
    f32x4 acc[4][4] = {};
    gemm_tile<6, 256>(bufA, Wp1, w * 64, lr, lg, acc);
    epilogue_relu(acc, b1, bufB, w * 64, lr, lg);
  }
  __syncthreads();

  // ---- GEMM2: h2 = relu(h1 @ W2 + b2), K=256 -> bufA
  {
    f32x4 acc[4][4] = {};
    gemm_tile<8, 256>(bufB, Wp2, w * 64, lr, lg, acc);
    epilogue_relu(acc, b2, bufA, w * 64, lr, lg);
  }
  __syncthreads();

  // ---- heads: alpha/beta = softplus(h2 @ [Wa|Wb] + [ba|bb]) + eps; v -> vbuf
  // wave w owns rows 16w..16w+15 (A row = lane&15), 64 packed cols.
  {
    f32x4 acc3[4] = {};
#pragma unroll
    for (int kb = 0; kb < 8; ++kb) {
      bf16x8 a = *reinterpret_cast<const bf16x8*>(bufA + swz_idx(16 * w + lr, kb * 32 + 8 * lg));
#pragma unroll
      for (int n = 0; n < 4; ++n) {
        bf16x8 b = *reinterpret_cast<const bf16x8*>(Wpab + ((kb * 64 + 16 * n + lr) << 5) + 8 * lg);
        acc3[n] = __builtin_amdgcn_mfma_f32_16x16x32_bf16(a, b, acc3[n], 0, 0, 0);
      }
    }
    float uu  = u[0] * 0.98f + 0.01f;
    float l2u = log2f(uu);
    float* vbuf = reinterpret_cast<float*>(bufB);   // bufB (h1) is dead now
#pragma unroll
    for (int n = 0; n < 2; ++n) {
      int j = 16 * n + lr;
      bool valid = (j < K_DIM);
      float bva = valid ? ba[j] : 0.f;
      float bvb = valid ? bb[j] : 0.f;
#pragma unroll
      for (int i = 0; i < 4; ++i) {
        int row = 16 * w + 4 * lg + i;
        if (valid) {
          float alpha = softplus_f(acc3[n][i] + bva) + 1e-4f;
          float beta  = softplus_f(acc3[n + 2][i] + bvb) + 1e-4f;
          size_t gro = (size_t)(r0 + row);
          outAlpha[gro * K_DIM + j] = alpha;
          outBeta [gro * K_DIM + j] = beta;
          float v;
          if (j == K_DIM - 1) v = 1.f;
          else {
            float t = exp2f(l2u / beta);          // uu^(1/beta), t<1
            v = exp2f(log2f(1.f - t) / alpha);    // (1-t)^(1/alpha)
          }
          vbuf[row * 33 + j] = v;                 // stride 33: conflict-free scan
        }
      }
    }
  }
  __syncthreads();

  // ---- stick-breaking scan: thread t<64 owns row t; pi -> d_out + bufA(bf16, stride 40)
  if (tid < 64) {
    const float* vbuf = reinterpret_cast<const float*>(bufB);
    int row = tid;
    size_t gro = (size_t)(r0 + row);
    float ex = 1.f;
#pragma unroll
    for (int j = 0; j < K_DIM - 1; ++j) {
      float vj = vbuf[row * 33 + j];
      float pi = vj * ex;
      outPi[gro * K_DIM + j] = pi;
      bufA[row * 40 + j] = __float2bfloat16(pi);
      ex *= (1.f - vj);
    }
    outPi[gro * K_DIM + (K_DIM - 1)] = ex;        // v_K forced to 1
    bufA[row * 40 + 29] = __float2bfloat16(ex);
    bufA[row * 40 + 30] = __float2bfloat16(0.f);  // K padded to 32
    bufA[row * 40 + 31] = __float2bfloat16(0.f);
  }
  __syncthreads();

  // ---- GEMM4: d = relu(pi @ Wd1 + bd1), K=32 (1 k-step) -> bufB
  {
    f32x4 acc[4][4] = {};
    bf16x8 a[4];
#pragma unroll
    for (int m = 0; m < 4; ++m)
      a[m] = *reinterpret_cast<const bf16x8*>(bufA + (16 * m + lr) * 40 + 8 * lg);
#pragma unroll
    for (int n = 0; n < 4; ++n) {
      bf16x8 b = *reinterpret_cast<const bf16x8*>(Wpd1 + ((w * 64 + 16 * n + lr) << 5) + 8 * lg);
#pragma unroll
      for (int m = 0; m < 4; ++m)
        acc[m][n] = __builtin_amdgcn_mfma_f32_16x16x32_bf16(a[m], b, acc[m][n], 0, 0, 0);
    }
    epilogue_relu(acc, bd1, bufB, w * 64, lr, lg);
  }
  __syncthreads();

  // ---- GEMM5: recon = sigmoid(d @ Wd2 + bd2), out cols padded to 192; wave w: cols 48w..48w+47
  {
    f32x4 acc[4][3] = {};
#pragma unroll
    for (int kb = 0; kb < 8; ++kb) {
      bf16x8 a[4];
#pragma unroll
      for (int m = 0; m < 4; ++m)
        a[m] = *reinterpret_cast<const bf16x8*>(bufB + swz_idx(16 * m + lr, kb * 32 + 8 * lg));
#pragma unroll
      for (int n = 0; n < 3; ++n) {
        bf16x8 b = *reinterpret_cast<const bf16x8*>(Wpd2 + ((kb * 192 + w * 48 + 16 * n + lr) << 5) + 8 * lg);
#pragma unroll
        for (int m = 0; m < 4; ++m)
          acc[m][n] = __builtin_amdgcn_mfma_f32_16x16x32_bf16(a[m], b, acc[m][n], 0, 0, 0);
      }
    }
#pragma unroll
    for (int n = 0; n < 3; ++n) {
      int col = w * 48 + 16 * n + lr;
      if (col < D_IN) {
        float bv = bd2[col];
#pragma unroll
        for (int m = 0; m < 4; ++m)
#pragma unroll
          for (int i = 0; i < 4; ++i) {
            int row = 16 * m + 4 * lg + i;
            float x = acc[m][n][i] + bv;
            float s = 1.f / (1.f + __expf(-x));
            outRecon[(size_t)(r0 + row) * D_IN + col] = s;
          }
      }
    }
  }
}

extern "C" void kernel_launch(void* const* d_in, const int* in_sizes, int n_in,
                              void* d_out, int out_size, void* d_ws, size_t ws_size,
                              hipStream_t stream) {
  const float* Yh  = (const float*)d_in[0];
  const float* u   = (const float*)d_in[1];
  const float* W1  = (const float*)d_in[2];
  const float* b1  = (const float*)d_in[3];
  const float* W2  = (const float*)d_in[4];
  const float* b2  = (const float*)d_in[5];
  const float* Wa  = (const float*)d_in[6];
  const float* ba  = (const float*)d_in[7];
  const float* Wb  = (const float*)d_in[8];
  const float* bb  = (const float*)d_in[9];
  const float* Wd1 = (const float*)d_in[10];
  const float* bd1 = (const float*)d_in[11];
  const float* Wd2 = (const float*)d_in[12];
  const float* bd2 = (const float*)d_in[13];

  bf16_t* ws   = (bf16_t*)d_ws;
  bf16_t* Wp1  = ws;                  // 6*256*32 = 49152 elems
  bf16_t* Wp2  = Wp1 + 49152;         // 8*256*32 = 65536
  bf16_t* Wpab = Wp2 + 65536;         // 8*64*32  = 16384
  bf16_t* Wpd1 = Wpab + 16384;        // 1*256*32 = 8192
  bf16_t* Wpd2 = Wpd1 + 8192;         // 8*192*32 = 49152   (total 376,832 B)

  float* outRecon = (float*)d_out;
  float* outAlpha = outRecon + (size_t)N_ROWS * D_IN;
  float* outBeta  = outAlpha + (size_t)N_ROWS * K_DIM;
  float* outPi    = outBeta  + (size_t)N_ROWS * K_DIM;

  pack_b_kernel<<<192, 256, 0, stream>>>(W1, Wp1, 162, 256, 256, 6);
  pack_b_kernel<<<256, 256, 0, stream>>>(W2, Wp2, 256, 256, 256, 8);
  pack_ab_kernel<<<64, 256, 0, stream>>>(Wa, Wb, Wpab);
  pack_b_kernel<<<32, 256, 0, stream>>>(Wd1, Wpd1, 30, 256, 256, 1);
  pack_b_kernel<<<192, 256, 0, stream>>>(Wd2, Wpd2, 256, 162, 192, 8);

  usdn_fused<<<N_ROWS / 64, 256, 0, stream>>>(Yh, u, b1, b2, ba, bb, bd1, bd2,
                                              Wp1, Wp2, Wpab, Wpd1, Wpd2,
                                              outRecon, outAlpha, outBeta, outPi);
}